// Round 11
// baseline (303.380 us; speedup 1.0000x reference)
//
#include <hip/hip_runtime.h>
#include <hip/hip_bf16.h>
#include <stdint.h>

typedef __bf16 bf16x8 __attribute__((ext_vector_type(8)));
typedef float  f32x4  __attribute__((ext_vector_type(4)));
typedef unsigned short u16x8 __attribute__((ext_vector_type(8)));

#define TC 32   // timesteps per chunk
#define NC 128  // chunks (TC*NC == 4096)
#define TH 16   // staged half

__device__ __forceinline__ unsigned short f2bf(float f) {
  unsigned u = __builtin_bit_cast(unsigned, f);
  unsigned r = (u + 0x7fffu + ((u >> 16) & 1u)) >> 16;
  return (unsigned short)r;
}
__device__ __forceinline__ float bf2f(unsigned short s) {
  unsigned u = ((unsigned)s) << 16;
  return __builtin_bit_cast(float, u);
}

__device__ __forceinline__ void gload_lds16(const void* g, void* l) {
  __builtin_amdgcn_global_load_lds(
      (const __attribute__((address_space(1))) unsigned int*)(g),
      (__attribute__((address_space(3))) unsigned int*)(l),
      16, 0, 0);
}

// rp[k] = r^(k+1), k=0..15, via full-rate mul tree (depth <= 4)
__device__ __forceinline__ void rpowers(float r, float* rp) {
  float r2 = r * r, r4 = r2 * r2, r8 = r4 * r4;
  rp[0] = r;        rp[1] = r2;       rp[2] = r2 * r;   rp[3] = r4;
  rp[4] = r4 * r;   rp[5] = r4 * r2;  rp[6] = rp[5] * r; rp[7] = r8;
  rp[8] = r8 * r;   rp[9] = r8 * r2;  rp[10] = rp[9] * r; rp[11] = r8 * r4;
  rp[12] = rp[11] * r; rp[13] = rp[11] * r2; rp[14] = rp[13] * r; rp[15] = r8 * r8;
}

// ---------------- fused prep: casts + pad (one launch) ----------------
__global__ __launch_bounds__(256) void prep_k(
    const float4* __restrict__ x, const float4* __restrict__ ipw,
    const float4* __restrict__ opw, const float* __restrict__ xpw,
    ushort4* __restrict__ xb, ushort4* __restrict__ wb1,
    ushort4* __restrict__ wb2, unsigned short* __restrict__ xwp)
{
  const int r = blockIdx.y;
  int i = blockIdx.x * 256 + threadIdx.x;
  const int stride = gridDim.x * 256;
  if (r == 0) {
    for (; i < 2097152; i += stride) {
      float4 v = x[i]; ushort4 o;
      o.x = f2bf(v.x); o.y = f2bf(v.y); o.z = f2bf(v.z); o.w = f2bf(v.w);
      xb[i] = o;
    }
  } else if (r == 1) {
    for (; i < 1048576; i += stride) {
      float4 v = ipw[i]; ushort4 o;
      o.x = f2bf(v.x); o.y = f2bf(v.y); o.z = f2bf(v.z); o.w = f2bf(v.w);
      wb1[i] = o;
    }
  } else if (r == 2) {
    for (; i < 524288; i += stride) {
      float4 v = opw[i]; ushort4 o;
      o.x = f2bf(v.x); o.y = f2bf(v.y); o.z = f2bf(v.z); o.w = f2bf(v.w);
      wb2[i] = o;
    }
  } else {
    for (; i < 262144; i += stride) {
      int row = i >> 11, col = i & 2047;
      xwp[i] = (row < 33) ? f2bf(xpw[row * 2048 + col]) : (unsigned short)0;
    }
  }
}

// ================= 8-phase 256x256 BK=64 MFMA GEMM (T2+T3+T4+T5) =================
// Single barrier per phase: wave skew < 1 phase; every STAGE target is provably
// untouched by any concurrent reader. Boundary vmcnt(4) covers async arrival.
template <bool BF16OUT, bool SWZ>
__global__ __launch_bounds__(512) void gemm8p(
    const unsigned short* __restrict__ A, const unsigned short* __restrict__ B,
    void* __restrict__ Cv, int M, int N, int K)
{
  __shared__ __align__(16) unsigned short As[2][2][8192];
  __shared__ __align__(16) unsigned short Bs[2][2][8192];
  const int tid = threadIdx.x;

  const int grid_m = M >> 8, grid_n = N >> 8;
  const int nwg = grid_m * grid_n;
  int wid = blockIdx.x;
  if (SWZ) { int q = nwg >> 3; wid = (wid & 7) * q + (wid >> 3); }  // nwg % 8 == 0
  const int GM = 8;
  const int nig = GM * grid_n;
  const int gidg = wid / nig;
  const int rem = wid - gidg * nig;
  const int fm = gidg * GM;
  const int gsz = (grid_m - fm < GM) ? (grid_m - fm) : GM;
  const int pm = fm + rem % gsz;
  const int pn = rem / gsz;
  const int m0 = pm << 8, n0 = pn << 8;

  const int NT = K >> 6;

  const int wq = tid >> 6, l = tid & 63;
  const int wr2 = wq >> 2, wc2 = wq & 3;
  const int lr = l & 15, q16 = l >> 4;
  const int sw = lr & 7;

  const unsigned short* aH0 = A + (size_t)m0 * K;
  const unsigned short* aH1 = A + (size_t)(m0 + 128) * K;
  const unsigned short* bH0 = B + (size_t)n0 * K;
  const unsigned short* bH1 = B + (size_t)(n0 + 128) * K;

#define STAGE8(srcbase, dstp, kt)                                              \
  { _Pragma("unroll") for (int i = 0; i < 2; ++i) {                            \
      int q = tid + 512 * i; int rw = q >> 3; int ssl = (q & 7) ^ (rw & 7);    \
      gload_lds16((srcbase) + (size_t)rw * K + (size_t)(kt) * 64 + ssl * 8,    \
                  (dstp) + q * 8); } }

#define LDA8(dd, MH)                                                           \
  { _Pragma("unroll") for (int mi = 0; mi < 4; ++mi) {                         \
      int ar = (wr2 * 64 + mi * 16 + lr) * 64;                                 \
      _Pragma("unroll") for (int ks = 0; ks < 2; ++ks)                         \
        af[mi][ks] = *(const bf16x8*)&As[dd][MH][ar + (((ks * 4 + q16) ^ sw) << 3)]; } }

#define LDB8(dd, NH)                                                           \
  { _Pragma("unroll") for (int ni = 0; ni < 2; ++ni) {                         \
      int br = (wc2 * 32 + ni * 16 + lr) * 64;                                 \
      _Pragma("unroll") for (int ks = 0; ks < 2; ++ks)                         \
        bf[NH][ni][ks] = *(const bf16x8*)&Bs[dd][NH][br + (((ks * 4 + q16) ^ sw) << 3)]; } }

#define MMA8(MH, NH)                                                           \
  { __builtin_amdgcn_s_setprio(1);                                             \
    _Pragma("unroll") for (int mi = 0; mi < 4; ++mi)                           \
    _Pragma("unroll") for (int ni = 0; ni < 2; ++ni)                           \
    _Pragma("unroll") for (int ks = 0; ks < 2; ++ks)                           \
      acc[MH][NH][mi][ni] = __builtin_amdgcn_mfma_f32_16x16x32_bf16(           \
          af[mi][ks], bf[NH][ni][ks], acc[MH][NH][mi][ni], 0, 0, 0);           \
    __builtin_amdgcn_s_setprio(0); }

  f32x4 acc[2][2][4][2];
#pragma unroll
  for (int a = 0; a < 2; ++a)
#pragma unroll
    for (int b = 0; b < 2; ++b)
#pragma unroll
      for (int c = 0; c < 4; ++c)
#pragma unroll
        for (int d = 0; d < 2; ++d)
          acc[a][b][c][d] = (f32x4){0.f, 0.f, 0.f, 0.f};

  bf16x8 af[4][2];
  bf16x8 bf[2][2][2];

  // ---- prologue ----
  STAGE8(aH0, As[0][0], 0);
  STAGE8(bH1, Bs[0][1], 0);
  STAGE8(aH1, As[0][1], 0);
  STAGE8(bH0, Bs[0][0], 0);
  if (NT > 1) {
    STAGE8(aH0, As[1][0], 1);
    STAGE8(bH1, Bs[1][1], 1);
    asm volatile("s_waitcnt vmcnt(4)" ::: "memory");
  } else {
    asm volatile("s_waitcnt vmcnt(0)" ::: "memory");
  }
  __builtin_amdgcn_s_barrier();

  for (int t = 0; t < NT; ++t) {
    const int d = t & 1;
    LDA8(d, 0); LDB8(d, 0);
    if (t + 1 < NT) STAGE8(aH1, As[(t + 1) & 1][1], t + 1);
    MMA8(0, 0);
    __builtin_amdgcn_s_barrier();
    LDB8(d, 1);
    if (t + 1 < NT) STAGE8(bH0, Bs[(t + 1) & 1][0], t + 1);
    MMA8(0, 1);
    __builtin_amdgcn_s_barrier();
    LDA8(d, 1);
    if (t + 2 < NT) STAGE8(aH0, As[d][0], t + 2);
    MMA8(1, 1);
    __builtin_amdgcn_s_barrier();
    if (t + 2 < NT) STAGE8(bH1, Bs[d][1], t + 2);
    MMA8(1, 0);
    if (t + 2 < NT) asm volatile("s_waitcnt vmcnt(4)" ::: "memory");
    else            asm volatile("s_waitcnt vmcnt(0)" ::: "memory");
    __builtin_amdgcn_s_barrier();
  }

#pragma unroll
  for (int mh = 0; mh < 2; ++mh)
#pragma unroll
    for (int nh = 0; nh < 2; ++nh)
#pragma unroll
      for (int mi = 0; mi < 4; ++mi)
#pragma unroll
        for (int ni = 0; ni < 2; ++ni) {
          int gr = m0 + mh * 128 + wr2 * 64 + mi * 16 + q16 * 4;
          int gc = n0 + nh * 128 + wc2 * 32 + ni * 16 + lr;
#pragma unroll
          for (int j = 0; j < 4; ++j) {
            if (BF16OUT)
              ((unsigned short*)Cv)[(size_t)(gr + j) * N + gc] = f2bf(acc[mh][nh][mi][ni][j]);
            else
              ((float*)Cv)[(size_t)(gr + j) * N + gc] = acc[mh][nh][mi][ni][j];
          }
        }
#undef STAGE8
#undef LDA8
#undef LDB8
#undef MMA8
}

// ---------------- 2-phase 128x128 GEMM (out_proj + split-K x_proj) ----------------
template <bool BF16OUT, bool SWZ>
__global__ __launch_bounds__(256) void gemm2p(
    const unsigned short* __restrict__ A, const unsigned short* __restrict__ B,
    void* __restrict__ Cv, int M, int N, int K)
{
  __shared__ __align__(16) unsigned short AsB[3 * 128 * 32];
  __shared__ __align__(16) unsigned short BsB[3 * 128 * 32];
  const int tid = threadIdx.x;

  const int grid_m = M >> 7, grid_n = N >> 7;
  const int nwg = grid_m * grid_n;
  int wid = blockIdx.x;
  if (SWZ) { int q = nwg >> 3; wid = (wid & 7) * q + (wid >> 3); }  // nwg % 8 == 0
  const int GM = 16;
  const int nig = GM * grid_n;
  const int gidg = wid / nig;
  const int rem = wid - gidg * nig;
  const int fm = gidg * GM;
  const int gsz = (grid_m - fm < GM) ? (grid_m - fm) : GM;
  const int pm = fm + rem % gsz;
  const int pn = rem / gsz;
  const int m0 = pm << 7, n0 = pn << 7;

  const int kseg = K / gridDim.z;
  const int kbeg = blockIdx.z * kseg;
  const int NT = kseg >> 5;

  const int w = tid >> 6, l = tid & 63;
  const int wr = w >> 1, wc = w & 1;
  const int lr = l & 15, kk = (l >> 4) * 8;

  f32x4 acc[4][4];
#pragma unroll
  for (int mi = 0; mi < 4; ++mi)
#pragma unroll
    for (int ni = 0; ni < 4; ++ni)
      acc[mi][ni] = (f32x4){0.f, 0.f, 0.f, 0.f};

#pragma unroll
  for (int tt = 0; tt < 2; ++tt) {
    unsigned short* as = AsB + tt * 4096;
    unsigned short* bs = BsB + tt * 4096;
    int k0 = kbeg + tt * 32;
#pragma unroll
    for (int i = 0; i < 2; ++i) {
      int q = tid + 256 * i;
      int row = q >> 2, sub = (q & 3) ^ ((q >> 3) & 3);
      gload_lds16(A + (size_t)(m0 + row) * K + k0 + sub * 8, as + q * 8);
      gload_lds16(B + (size_t)(n0 + row) * K + k0 + sub * 8, bs + q * 8);
    }
  }
  asm volatile("s_waitcnt vmcnt(4)\n\ts_barrier" ::: "memory");

  for (int t = 0; t < NT; ++t) {
    if (t + 2 < NT) {
      unsigned short* as = AsB + ((t + 2) % 3) * 4096;
      unsigned short* bs = BsB + ((t + 2) % 3) * 4096;
      int k0 = kbeg + (t + 2) * 32;
#pragma unroll
      for (int i = 0; i < 2; ++i) {
        int q = tid + 256 * i;
        int row = q >> 2, sub = (q & 3) ^ ((q >> 3) & 3);
        gload_lds16(A + (size_t)(m0 + row) * K + k0 + sub * 8, as + q * 8);
        gload_lds16(B + (size_t)(n0 + row) * K + k0 + sub * 8, bs + q * 8);
      }
    }
    const unsigned short* as = AsB + (t % 3) * 4096;
    const unsigned short* bs = BsB + (t % 3) * 4096;
    bf16x8 af[4], bfr[4];
#pragma unroll
    for (int mi = 0; mi < 4; ++mi) {
      int row = wr * 64 + mi * 16 + lr;
      int col = kk ^ (((row >> 1) & 3) << 3);
      af[mi] = *(const bf16x8*)&as[row * 32 + col];
    }
#pragma unroll
    for (int ni = 0; ni < 4; ++ni) {
      int row = wc * 64 + ni * 16 + lr;
      int col = kk ^ (((row >> 1) & 3) << 3);
      bfr[ni] = *(const bf16x8*)&bs[row * 32 + col];
    }
    __builtin_amdgcn_s_setprio(1);
#pragma unroll
    for (int mi = 0; mi < 4; ++mi)
#pragma unroll
      for (int ni = 0; ni < 4; ++ni)
        acc[mi][ni] = __builtin_amdgcn_mfma_f32_16x16x32_bf16(af[mi], bfr[ni], acc[mi][ni], 0, 0, 0);
    __builtin_amdgcn_s_setprio(0);
    if (t + 1 < NT) {
      if (t + 2 < NT) asm volatile("s_waitcnt vmcnt(4)\n\ts_barrier" ::: "memory");
      else            asm volatile("s_waitcnt vmcnt(0)\n\ts_barrier" ::: "memory");
    }
  }

#pragma unroll
  for (int mi = 0; mi < 4; ++mi)
#pragma unroll
    for (int ni = 0; ni < 4; ++ni) {
      int gr = m0 + wr * 64 + mi * 16 + (l >> 4) * 4;
      int gc = n0 + wc * 64 + ni * 16 + (l & 15);
#pragma unroll
      for (int j = 0; j < 4; ++j) {
        if (BF16OUT)
          ((unsigned short*)Cv)[(size_t)(gr + j) * N + gc] = f2bf(acc[mi][ni][j]);
        else
          ((float*)Cv + (size_t)blockIdx.z * M * N)[(size_t)(gr + j) * N + gc] = acc[mi][ni][j];
      }
    }
}

// reduce 4 partial C buffers -> dbc (1M floats, float4)
__global__ __launch_bounds__(256) void redux4_k(const float4* __restrict__ part,
                                                float4* __restrict__ out) {
  int i = blockIdx.x * 256 + threadIdx.x;   // 262144 float4
  const int STR = 262144;
  float4 a = part[i], b = part[i + STR], c = part[i + 2 * STR], d = part[i + 3 * STR];
  out[i] = make_float4(a.x + b.x + c.x + d.x, a.y + b.y + c.y + d.y,
                       a.z + b.z + c.z + d.z, a.w + b.w + c.w + d.w);
}

// ---------------- depthwise causal conv(4) + bias + SiLU (bf16 in/out) ----------------
#define CONV_L 8
__global__ __launch_bounds__(256) void conv_silu_k(
    const unsigned short* __restrict__ xzb, const float* __restrict__ cw,
    const float* __restrict__ cb, unsigned short* __restrict__ xsb)
{
  const int b = blockIdx.y;
  const int l0 = blockIdx.x * CONV_L;
  const int d = threadIdx.x * 8;
  float w[4][8], bias[8];
#pragma unroll
  for (int i = 0; i < 8; ++i) {
    bias[i] = cb[d + i];
#pragma unroll
    for (int j = 0; j < 4; ++j) w[j][i] = cw[(d + i) * 4 + j];
  }
  const size_t rb = (size_t)b * 4096;
  float win[3][8];
#pragma unroll
  for (int j = 0; j < 3; ++j) {
    int l = l0 - 3 + j;
    if (l >= 0) {
      u16x8 v = *(const u16x8*)(xzb + (rb + l) * 4096 + d);
#pragma unroll
      for (int i = 0; i < 8; ++i) win[j][i] = bf2f(v[i]);
    } else {
#pragma unroll
      for (int i = 0; i < 8; ++i) win[j][i] = 0.f;
    }
  }
  for (int l = l0; l < l0 + CONV_L; ++l) {
    u16x8 v = *(const u16x8*)(xzb + (rb + l) * 4096 + d);
    float cur[8]; u16x8 ob;
#pragma unroll
    for (int i = 0; i < 8; ++i) {
      cur[i] = bf2f(v[i]);
      float u = bias[i] + w[0][i] * win[0][i] + w[1][i] * win[1][i]
                        + w[2][i] * win[2][i] + w[3][i] * cur[i];
      float s = u / (1.f + __expf(-u));
      ob[i] = f2bf(s);
    }
    *(u16x8*)(xsb + (rb + l) * 2048 + d) = ob;
#pragma unroll
    for (int i = 0; i < 8; ++i) { win[0][i] = win[1][i]; win[1][i] = win[2][i]; win[2][i] = cur[i]; }
  }
}

// ---------------- chunk-parallel selective scan ----------------
__global__ __launch_bounds__(256) void scan_p1(
    const unsigned short* __restrict__ xsb16, const float* __restrict__ dbc,
    const float* __restrict__ dtw, const float* __restrict__ dtb,
    const float* __restrict__ alog,
    float* __restrict__ Sg, float* __restrict__ cdg)
{
  const int chunk = blockIdx.x;
  const int d0 = blockIdx.y * 256;
  const int b = blockIdx.z;
  const int tid = threadIdx.x;
  const size_t rowbase = (size_t)b * 4096 + chunk * TC;

  __shared__ __align__(16) unsigned short xsS[TH][256];
  __shared__ __align__(16) float bS[TC][16];
  __shared__ float drS[TC];

  if (tid < TC) drS[tid] = dbc[(rowbase + tid) * 128];
  for (int i = tid; i < TC * 16; i += 256) {
    int t = i >> 4, q = i & 15;
    bS[t][q] = dbc[(rowbase + t) * 128 + 1 + q];
  }

  const int d = d0 + tid;
  const float wdt = dtw[d], bdt = dtb[d];
  float adn[16];
  bool ok = true;
#pragma unroll
  for (int k = 0; k < 4; ++k) {
    float4 a4 = *(const float4*)(alog + (size_t)d * 16 + k * 4);
    adn[4 * k + 0] = -__expf(a4.x); adn[4 * k + 1] = -__expf(a4.y);
    adn[4 * k + 2] = -__expf(a4.z); adn[4 * k + 3] = -__expf(a4.w);
  }
#pragma unroll
  for (int n = 0; n < 16; ++n)
    ok = ok && (fabsf(adn[n] + (float)(n + 1)) <= 1e-3f * (float)(n + 1));

  float h[16];
#pragma unroll
  for (int n = 0; n < 16; ++n) h[n] = 0.f;
  float cd = 0.f;

  for (int half = 0; half < 2; ++half) {
    if (half) __syncthreads();
    for (int i = tid; i < TH * 32; i += 256) {
      int tt = i >> 5, q = i & 31;
      *(u16x8*)&xsS[tt][q * 8] =
          *(const u16x8*)(xsb16 + (rowbase + half * TH + tt) * 2048 + d0 + q * 8);
    }
    __syncthreads();

    if (ok) {
      for (int tt = 0; tt < TH; ++tt) {
        int t = half * TH + tt;
        float pre = fmaf(drS[t], wdt, bdt);
        float e = __expf(pre);
        float dlt = (pre > 20.f) ? pre : __logf(1.f + e);
        float xv = bf2f(xsS[tt][tid]);
        float dx = dlt * xv;
        cd += dlt;
        float r = __expf(-dlt);
        float rp[16];
        rpowers(r, rp);
        f32x4 Bv[4];
#pragma unroll
        for (int k = 0; k < 4; ++k) Bv[k] = ((const f32x4*)&bS[t][0])[k];
#pragma unroll
        for (int n = 0; n < 16; ++n)
          h[n] = fmaf(rp[n], h[n], dx * Bv[n >> 2][n & 3]);
      }
    } else {
      for (int tt = 0; tt < TH; ++tt) {
        int t = half * TH + tt;
        float pre = fmaf(drS[t], wdt, bdt);
        float e = __expf(pre);
        float dlt = (pre > 20.f) ? pre : __logf(1.f + e);
        float xv = bf2f(xsS[tt][tid]);
        float dx = dlt * xv;
        cd += dlt;
        f32x4 Bv[4];
#pragma unroll
        for (int k = 0; k < 4; ++k) Bv[k] = ((const f32x4*)&bS[t][0])[k];
#pragma unroll
        for (int n = 0; n < 16; ++n) {
          float dA = __expf(adn[n] * dlt);
          h[n] = fmaf(dA, h[n], dx * Bv[n >> 2][n & 3]);
        }
      }
    }
  }
  cdg[(size_t)(b * NC + chunk) * 2048 + d] = cd;
  float* Sp = Sg + ((size_t)(b * NC + chunk) * 32768 + (size_t)d * 16);
#pragma unroll
  for (int k = 0; k < 4; ++k)
    ((float4*)Sp)[k] = make_float4(h[4 * k], h[4 * k + 1], h[4 * k + 2], h[4 * k + 3]);
}

// Phase 2: prefix scan across chunks, IN-PLACE: Sg[c] := state entering chunk c.
// Each thread owns a full (b,dn) chunk-column -> no cross-thread hazard.
__global__ __launch_bounds__(256) void scan_p2(
    float* __restrict__ Sg, const float* __restrict__ cdg,
    const float* __restrict__ alog)
{
  int g = blockIdx.x * 256 + threadIdx.x;   // 65536 = B*D*N
  int b = g >> 15, dn = g & 32767;
  int d = dn >> 4;
  float adn = -__expf(alog[dn]);
  float h = 0.f;
  for (int c = 0; c < NC; ++c) {
    size_t o = (size_t)(b * NC + c) * 32768 + dn;
    float S = Sg[o];
    float P = __expf(adn * cdg[(size_t)(b * NC + c) * 2048 + d]);
    Sg[o] = h;
    h = fmaf(P, h, S);
  }
}

__global__ __launch_bounds__(256) void scan_p3(
    const unsigned short* __restrict__ xsb16, const float* __restrict__ dbc,
    const float* __restrict__ dtw, const float* __restrict__ dtb,
    const float* __restrict__ alog, const float* __restrict__ Dp,
    const unsigned short* __restrict__ xzb, const float* __restrict__ Hg,
    unsigned short* __restrict__ gb)
{
  const int chunk = blockIdx.x;
  const int d0 = blockIdx.y * 256;
  const int b = blockIdx.z;
  const int tid = threadIdx.x;
  const size_t rowbase = (size_t)b * 4096 + chunk * TC;

  __shared__ __align__(16) unsigned short xsS[TH][256];
  __shared__ __align__(16) float bcS[TC][32];

  for (int i = tid; i < TC * 32; i += 256) {
    int t = i >> 5, q = i & 31;
    bcS[t][q] = dbc[(rowbase + t) * 128 + 1 + q];
  }

  const int d = d0 + tid;
  const float wdt = dtw[d], bdt = dtb[d], Dd = Dp[d];
  const float* __restrict__ drp = dbc + rowbase * 128;
  float adn[16];
  bool ok = true;
#pragma unroll
  for (int k = 0; k < 4; ++k) {
    float4 a4 = *(const float4*)(alog + (size_t)d * 16 + k * 4);
    adn[4 * k + 0] = -__expf(a4.x); adn[4 * k + 1] = -__expf(a4.y);
    adn[4 * k + 2] = -__expf(a4.z); adn[4 * k + 3] = -__expf(a4.w);
  }
#pragma unroll
  for (int n = 0; n < 16; ++n)
    ok = ok && (fabsf(adn[n] + (float)(n + 1)) <= 1e-3f * (float)(n + 1));

  float h[16];
  {
    const float* Hp = Hg + ((size_t)(b * NC + chunk) * 32768 + (size_t)d * 16);
#pragma unroll
    for (int k = 0; k < 4; ++k) {
      float4 h4 = ((const float4*)Hp)[k];
      h[4 * k + 0] = h4.x; h[4 * k + 1] = h4.y; h[4 * k + 2] = h4.z; h[4 * k + 3] = h4.w;
    }
  }

  for (int half = 0; half < 2; ++half) {
    if (half) __syncthreads();
    for (int i = tid; i < TH * 32; i += 256) {
      int tt = i >> 5, q = i & 31;
      *(u16x8*)&xsS[tt][q * 8] =
          *(const u16x8*)(xsb16 + (rowbase + half * TH + tt) * 2048 + d0 + q * 8);
    }
    __syncthreads();

    if (ok) {
      for (int tt = 0; tt < TH; ++tt) {
        int t = half * TH + tt;
        float pre = fmaf(drp[(size_t)t * 128], wdt, bdt);
        float e = __expf(pre);
        float dlt = (pre > 20.f) ? pre : __logf(1.f + e);
        float xv = bf2f(xsS[tt][tid]);
        float dx = dlt * xv;
        float r = __expf(-dlt);
        float rp[16];
        rpowers(r, rp);
        f32x4 Bv[4], Cv[4];
#pragma unroll
        for (int k = 0; k < 4; ++k) {
          Bv[k] = ((const f32x4*)&bcS[t][0])[k];
          Cv[k] = ((const f32x4*)&bcS[t][16])[k];
        }
        float yp[4];
        yp[0] = Dd * xv; yp[1] = 0.f; yp[2] = 0.f; yp[3] = 0.f;
#pragma unroll
        for (int n = 0; n < 16; ++n) {
          h[n] = fmaf(rp[n], h[n], dx * Bv[n >> 2][n & 3]);
          yp[n & 3] = fmaf(h[n], Cv[n >> 2][n & 3], yp[n & 3]);
        }
        float y = (yp[0] + yp[1]) + (yp[2] + yp[3]);
        xsS[tt][tid] = f2bf(y);
      }
    } else {
      for (int tt = 0; tt < TH; ++tt) {
        int t = half * TH + tt;
        float pre = fmaf(drp[(size_t)t * 128], wdt, bdt);
        float e = __expf(pre);
        float dlt = (pre > 20.f) ? pre : __logf(1.f + e);
        float xv = bf2f(xsS[tt][tid]);
        float dx = dlt * xv;
        f32x4 Bv[4], Cv[4];
#pragma unroll
        for (int k = 0; k < 4; ++k) {
          Bv[k] = ((const f32x4*)&bcS[t][0])[k];
          Cv[k] = ((const f32x4*)&bcS[t][16])[k];
        }
        float yp[4];
        yp[0] = Dd * xv; yp[1] = 0.f; yp[2] = 0.f; yp[3] = 0.f;
#pragma unroll
        for (int n = 0; n < 16; ++n) {
          float dA = __expf(adn[n] * dlt);
          h[n] = fmaf(dA, h[n], dx * Bv[n >> 2][n & 3]);
          yp[n & 3] = fmaf(h[n], Cv[n >> 2][n & 3], yp[n & 3]);
        }
        float y = (yp[0] + yp[1]) + (yp[2] + yp[3]);
        xsS[tt][tid] = f2bf(y);
      }
    }
    __syncthreads();

    for (int i = tid; i < TH * 32; i += 256) {
      int tt = i >> 5, q = i & 31;
      size_t row = rowbase + half * TH + tt;
      u16x8 yv = *(const u16x8*)&xsS[tt][q * 8];
      u16x8 zv = *(const u16x8*)(xzb + row * 4096 + 2048 + d0 + q * 8);
      u16x8 ov;
#pragma unroll
      for (int j = 0; j < 8; ++j) {
        float z = bf2f(zv[j]);
        float s = z / (1.f + __expf(-z));
        ov[j] = f2bf(bf2f(yv[j]) * s);
      }
      *(u16x8*)(gb + row * 2048 + d0 + q * 8) = ov;
    }
  }
}

extern "C" void kernel_launch(void* const* d_in, const int* in_sizes, int n_in,
                              void* d_out, int out_size, void* d_ws, size_t ws_size,
                              hipStream_t stream) {
  const float* x    = (const float*)d_in[0];
  const float* ipw  = (const float*)d_in[1];
  const float* cw   = (const float*)d_in[2];
  const float* cb   = (const float*)d_in[3];
  const float* xpw  = (const float*)d_in[4];
  const float* dtw  = (const float*)d_in[5];
  const float* dtb  = (const float*)d_in[6];
  const float* alog = (const float*)d_in[7];
  const float* Dp   = (const float*)d_in[8];
  const float* opw  = (const float*)d_in[9];
  float* out = (float*)d_out;

  char* p = (char*)d_ws;
  unsigned short* xb   = (unsigned short*)p; p += (size_t)8388608 * 2;   // x bf16           (16 MiB)
  unsigned short* wb1  = (unsigned short*)p; p += (size_t)4194304 * 2;   // in_proj_w bf16   (8 MiB)
  unsigned short* wb2  = (unsigned short*)p; p += (size_t)2097152 * 2;   // out_proj_w bf16  (4 MiB)
  unsigned short* xwp  = (unsigned short*)p; p += (size_t)262144 * 2;    // padded x_proj_w  (0.5 MiB)
  unsigned short* xzb  = (unsigned short*)p; p += (size_t)33554432 * 2;  // in_proj out bf16 (64 MiB)
  unsigned short* xsb16= (unsigned short*)p; p += (size_t)16777216 * 2;  // conv+silu bf16   (32 MiB)
  float*          dbc  = (float*)p;          p += (size_t)1048576 * 4;   // x_proj out fp32  (4 MiB)
  unsigned short* gb   = (unsigned short*)p; p += (size_t)16777216 * 2;  // y*silu(z) bf16   (32 MiB)
  float*          Sg   = (float*)p;          p += (size_t)8388608 * 4;   // chunk states S->H in-place (32 MiB)
  float*          cdg  = (float*)p;          p += (size_t)524288 * 4;    // chunk decay sums (2 MiB)
  float*          dbcp = Sg;                                             // 4 split-K partials (alias Sg, 16 MiB)

  prep_k<<<dim3(512, 4), 256, 0, stream>>>(
      (const float4*)x, (const float4*)ipw, (const float4*)opw, xpw,
      (ushort4*)xb, (ushort4*)wb1, (ushort4*)wb2, xwp);

  gemm8p<true, true><<<512, 512, 0, stream>>>(xb, wb1, xzb, 8192, 4096, 1024);
  conv_silu_k<<<dim3(4096 / CONV_L, 2), 256, 0, stream>>>(xzb, cw, cb, xsb16);

  gemm2p<false, false><<<dim3(64, 1, 4), 256, 0, stream>>>(xsb16, xwp, dbcp, 8192, 128, 2048);
  redux4_k<<<1024, 256, 0, stream>>>((const float4*)dbcp, (float4*)dbc);

  scan_p1<<<dim3(NC, 8, 2), 256, 0, stream>>>(xsb16, dbc, dtw, dtb, alog, Sg, cdg);
  scan_p2<<<256, 256, 0, stream>>>(Sg, cdg, alog);
  scan_p3<<<dim3(NC, 8, 2), 256, 0, stream>>>(xsb16, dbc, dtw, dtb, alog, Dp, xzb, Sg, gb);

  gemm2p<false, true><<<dim3(512, 1, 1), 256, 0, stream>>>(gb, wb2, out, 8192, 1024, 2048);
}

// Round 12
// 281.971 us; speedup vs baseline: 1.0759x; 1.0759x over previous
//
#include <hip/hip_runtime.h>
#include <hip/hip_bf16.h>
#include <stdint.h>

typedef __bf16 bf16x8 __attribute__((ext_vector_type(8)));
typedef float  f32x4  __attribute__((ext_vector_type(4)));
typedef float  f32x2  __attribute__((ext_vector_type(2)));
typedef unsigned short u16x8 __attribute__((ext_vector_type(8)));

#define TC 32   // timesteps per chunk
#define NC 128  // chunks (TC*NC == 4096)
#define TH 16   // staged half

__device__ __forceinline__ unsigned short f2bf(float f) {
  unsigned u = __builtin_bit_cast(unsigned, f);
  unsigned r = (u + 0x7fffu + ((u >> 16) & 1u)) >> 16;
  return (unsigned short)r;
}
__device__ __forceinline__ float bf2f(unsigned short s) {
  unsigned u = ((unsigned)s) << 16;
  return __builtin_bit_cast(float, u);
}

__device__ __forceinline__ void gload_lds16(const void* g, void* l) {
  __builtin_amdgcn_global_load_lds(
      (const __attribute__((address_space(1))) unsigned int*)(g),
      (__attribute__((address_space(3))) unsigned int*)(l),
      16, 0, 0);
}

// ---------------- fused prep: casts + pad (one launch) ----------------
__global__ __launch_bounds__(256) void prep_k(
    const float4* __restrict__ x, const float4* __restrict__ ipw,
    const float4* __restrict__ opw, const float* __restrict__ xpw,
    ushort4* __restrict__ xb, ushort4* __restrict__ wb1,
    ushort4* __restrict__ wb2, unsigned short* __restrict__ xwp)
{
  const int r = blockIdx.y;
  int i = blockIdx.x * 256 + threadIdx.x;
  const int stride = gridDim.x * 256;
  if (r == 0) {
    for (; i < 2097152; i += stride) {
      float4 v = x[i]; ushort4 o;
      o.x = f2bf(v.x); o.y = f2bf(v.y); o.z = f2bf(v.z); o.w = f2bf(v.w);
      xb[i] = o;
    }
  } else if (r == 1) {
    for (; i < 1048576; i += stride) {
      float4 v = ipw[i]; ushort4 o;
      o.x = f2bf(v.x); o.y = f2bf(v.y); o.z = f2bf(v.z); o.w = f2bf(v.w);
      wb1[i] = o;
    }
  } else if (r == 2) {
    for (; i < 524288; i += stride) {
      float4 v = opw[i]; ushort4 o;
      o.x = f2bf(v.x); o.y = f2bf(v.y); o.z = f2bf(v.z); o.w = f2bf(v.w);
      wb2[i] = o;
    }
  } else {
    for (; i < 262144; i += stride) {
      int row = i >> 11, col = i & 2047;
      xwp[i] = (row < 33) ? f2bf(xpw[row * 2048 + col]) : (unsigned short)0;
    }
  }
}

// ================= 8-phase 256x256 BK=64 MFMA GEMM (T2+T3+T4+T5) =================
template <bool BF16OUT, bool SWZ>
__global__ __launch_bounds__(512) void gemm8p(
    const unsigned short* __restrict__ A, const unsigned short* __restrict__ B,
    void* __restrict__ Cv, int M, int N, int K)
{
  __shared__ __align__(16) unsigned short As[2][2][8192];
  __shared__ __align__(16) unsigned short Bs[2][2][8192];
  const int tid = threadIdx.x;

  const int grid_m = M >> 8, grid_n = N >> 8;
  const int nwg = grid_m * grid_n;
  int wid = blockIdx.x;
  if (SWZ) { int q = nwg >> 3; wid = (wid & 7) * q + (wid >> 3); }  // nwg % 8 == 0
  const int GM = 8;
  const int nig = GM * grid_n;
  const int gidg = wid / nig;
  const int rem = wid - gidg * nig;
  const int fm = gidg * GM;
  const int gsz = (grid_m - fm < GM) ? (grid_m - fm) : GM;
  const int pm = fm + rem % gsz;
  const int pn = rem / gsz;
  const int m0 = pm << 8, n0 = pn << 8;

  const int NT = K >> 6;

  const int wq = tid >> 6, l = tid & 63;
  const int wr2 = wq >> 2, wc2 = wq & 3;
  const int lr = l & 15, q16 = l >> 4;
  const int sw = lr & 7;

  const unsigned short* aH0 = A + (size_t)m0 * K;
  const unsigned short* aH1 = A + (size_t)(m0 + 128) * K;
  const unsigned short* bH0 = B + (size_t)n0 * K;
  const unsigned short* bH1 = B + (size_t)(n0 + 128) * K;

#define STAGE8(srcbase, dstp, kt)                                              \
  { _Pragma("unroll") for (int i = 0; i < 2; ++i) {                            \
      int q = tid + 512 * i; int rw = q >> 3; int ssl = (q & 7) ^ (rw & 7);    \
      gload_lds16((srcbase) + (size_t)rw * K + (size_t)(kt) * 64 + ssl * 8,    \
                  (dstp) + q * 8); } }

#define LDA8(dd, MH)                                                           \
  { _Pragma("unroll") for (int mi = 0; mi < 4; ++mi) {                         \
      int ar = (wr2 * 64 + mi * 16 + lr) * 64;                                 \
      _Pragma("unroll") for (int ks = 0; ks < 2; ++ks)                         \
        af[mi][ks] = *(const bf16x8*)&As[dd][MH][ar + (((ks * 4 + q16) ^ sw) << 3)]; } }

#define LDB8(dd, NH)                                                           \
  { _Pragma("unroll") for (int ni = 0; ni < 2; ++ni) {                         \
      int br = (wc2 * 32 + ni * 16 + lr) * 64;                                 \
      _Pragma("unroll") for (int ks = 0; ks < 2; ++ks)                         \
        bf[NH][ni][ks] = *(const bf16x8*)&Bs[dd][NH][br + (((ks * 4 + q16) ^ sw) << 3)]; } }

#define MMA8(MH, NH)                                                           \
  { __builtin_amdgcn_s_setprio(1);                                             \
    _Pragma("unroll") for (int mi = 0; mi < 4; ++mi)                           \
    _Pragma("unroll") for (int ni = 0; ni < 2; ++ni)                           \
    _Pragma("unroll") for (int ks = 0; ks < 2; ++ks)                           \
      acc[MH][NH][mi][ni] = __builtin_amdgcn_mfma_f32_16x16x32_bf16(           \
          af[mi][ks], bf[NH][ni][ks], acc[MH][NH][mi][ni], 0, 0, 0);           \
    __builtin_amdgcn_s_setprio(0); }

  f32x4 acc[2][2][4][2];
#pragma unroll
  for (int a = 0; a < 2; ++a)
#pragma unroll
    for (int b = 0; b < 2; ++b)
#pragma unroll
      for (int c = 0; c < 4; ++c)
#pragma unroll
        for (int d = 0; d < 2; ++d)
          acc[a][b][c][d] = (f32x4){0.f, 0.f, 0.f, 0.f};

  bf16x8 af[4][2];
  bf16x8 bf[2][2][2];

  // ---- prologue ----
  STAGE8(aH0, As[0][0], 0);
  STAGE8(bH1, Bs[0][1], 0);
  STAGE8(aH1, As[0][1], 0);
  STAGE8(bH0, Bs[0][0], 0);
  if (NT > 1) {
    STAGE8(aH0, As[1][0], 1);
    STAGE8(bH1, Bs[1][1], 1);
    asm volatile("s_waitcnt vmcnt(4)" ::: "memory");
  } else {
    asm volatile("s_waitcnt vmcnt(0)" ::: "memory");
  }
  __builtin_amdgcn_s_barrier();

  for (int t = 0; t < NT; ++t) {
    const int d = t & 1;
    LDA8(d, 0); LDB8(d, 0);
    if (t + 1 < NT) STAGE8(aH1, As[(t + 1) & 1][1], t + 1);
    MMA8(0, 0);
    __builtin_amdgcn_s_barrier();
    LDB8(d, 1);
    if (t + 1 < NT) STAGE8(bH0, Bs[(t + 1) & 1][0], t + 1);
    MMA8(0, 1);
    __builtin_amdgcn_s_barrier();
    LDA8(d, 1);
    if (t + 2 < NT) STAGE8(aH0, As[d][0], t + 2);
    MMA8(1, 1);
    __builtin_amdgcn_s_barrier();
    if (t + 2 < NT) STAGE8(bH1, Bs[d][1], t + 2);
    MMA8(1, 0);
    if (t + 2 < NT) asm volatile("s_waitcnt vmcnt(4)" ::: "memory");
    else            asm volatile("s_waitcnt vmcnt(0)" ::: "memory");
    __builtin_amdgcn_s_barrier();
  }

#pragma unroll
  for (int mh = 0; mh < 2; ++mh)
#pragma unroll
    for (int nh = 0; nh < 2; ++nh)
#pragma unroll
      for (int mi = 0; mi < 4; ++mi)
#pragma unroll
        for (int ni = 0; ni < 2; ++ni) {
          int gr = m0 + mh * 128 + wr2 * 64 + mi * 16 + q16 * 4;
          int gc = n0 + nh * 128 + wc2 * 32 + ni * 16 + lr;
#pragma unroll
          for (int j = 0; j < 4; ++j) {
            if (BF16OUT)
              ((unsigned short*)Cv)[(size_t)(gr + j) * N + gc] = f2bf(acc[mh][nh][mi][ni][j]);
            else
              ((float*)Cv)[(size_t)(gr + j) * N + gc] = acc[mh][nh][mi][ni][j];
          }
        }
#undef STAGE8
#undef LDA8
#undef LDB8
#undef MMA8
}

// ---------------- 2-phase 128x128 GEMM (out_proj + split-K x_proj) ----------------
template <bool BF16OUT, bool SWZ>
__global__ __launch_bounds__(256) void gemm2p(
    const unsigned short* __restrict__ A, const unsigned short* __restrict__ B,
    void* __restrict__ Cv, int M, int N, int K)
{
  __shared__ __align__(16) unsigned short AsB[3 * 128 * 32];
  __shared__ __align__(16) unsigned short BsB[3 * 128 * 32];
  const int tid = threadIdx.x;

  const int grid_m = M >> 7, grid_n = N >> 7;
  const int nwg = grid_m * grid_n;
  int wid = blockIdx.x;
  if (SWZ) { int q = nwg >> 3; wid = (wid & 7) * q + (wid >> 3); }  // nwg % 8 == 0
  const int GM = 16;
  const int nig = GM * grid_n;
  const int gidg = wid / nig;
  const int rem = wid - gidg * nig;
  const int fm = gidg * GM;
  const int gsz = (grid_m - fm < GM) ? (grid_m - fm) : GM;
  const int pm = fm + rem % gsz;
  const int pn = rem / gsz;
  const int m0 = pm << 7, n0 = pn << 7;

  const int kseg = K / gridDim.z;
  const int kbeg = blockIdx.z * kseg;
  const int NT = kseg >> 5;

  const int w = tid >> 6, l = tid & 63;
  const int wr = w >> 1, wc = w & 1;
  const int lr = l & 15, kk = (l >> 4) * 8;

  f32x4 acc[4][4];
#pragma unroll
  for (int mi = 0; mi < 4; ++mi)
#pragma unroll
    for (int ni = 0; ni < 4; ++ni)
      acc[mi][ni] = (f32x4){0.f, 0.f, 0.f, 0.f};

#pragma unroll
  for (int tt = 0; tt < 2; ++tt) {
    unsigned short* as = AsB + tt * 4096;
    unsigned short* bs = BsB + tt * 4096;
    int k0 = kbeg + tt * 32;
#pragma unroll
    for (int i = 0; i < 2; ++i) {
      int q = tid + 256 * i;
      int row = q >> 2, sub = (q & 3) ^ ((q >> 3) & 3);
      gload_lds16(A + (size_t)(m0 + row) * K + k0 + sub * 8, as + q * 8);
      gload_lds16(B + (size_t)(n0 + row) * K + k0 + sub * 8, bs + q * 8);
    }
  }
  asm volatile("s_waitcnt vmcnt(4)\n\ts_barrier" ::: "memory");

  for (int t = 0; t < NT; ++t) {
    if (t + 2 < NT) {
      unsigned short* as = AsB + ((t + 2) % 3) * 4096;
      unsigned short* bs = BsB + ((t + 2) % 3) * 4096;
      int k0 = kbeg + (t + 2) * 32;
#pragma unroll
      for (int i = 0; i < 2; ++i) {
        int q = tid + 256 * i;
        int row = q >> 2, sub = (q & 3) ^ ((q >> 3) & 3);
        gload_lds16(A + (size_t)(m0 + row) * K + k0 + sub * 8, as + q * 8);
        gload_lds16(B + (size_t)(n0 + row) * K + k0 + sub * 8, bs + q * 8);
      }
    }
    const unsigned short* as = AsB + (t % 3) * 4096;
    const unsigned short* bs = BsB + (t % 3) * 4096;
    bf16x8 af[4], bfr[4];
#pragma unroll
    for (int mi = 0; mi < 4; ++mi) {
      int row = wr * 64 + mi * 16 + lr;
      int col = kk ^ (((row >> 1) & 3) << 3);
      af[mi] = *(const bf16x8*)&as[row * 32 + col];
    }
#pragma unroll
    for (int ni = 0; ni < 4; ++ni) {
      int row = wc * 64 + ni * 16 + lr;
      int col = kk ^ (((row >> 1) & 3) << 3);
      bfr[ni] = *(const bf16x8*)&bs[row * 32 + col];
    }
    __builtin_amdgcn_s_setprio(1);
#pragma unroll
    for (int mi = 0; mi < 4; ++mi)
#pragma unroll
      for (int ni = 0; ni < 4; ++ni)
        acc[mi][ni] = __builtin_amdgcn_mfma_f32_16x16x32_bf16(af[mi], bfr[ni], acc[mi][ni], 0, 0, 0);
    __builtin_amdgcn_s_setprio(0);
    if (t + 1 < NT) {
      if (t + 2 < NT) asm volatile("s_waitcnt vmcnt(4)\n\ts_barrier" ::: "memory");
      else            asm volatile("s_waitcnt vmcnt(0)\n\ts_barrier" ::: "memory");
    }
  }

#pragma unroll
  for (int mi = 0; mi < 4; ++mi)
#pragma unroll
    for (int ni = 0; ni < 4; ++ni) {
      int gr = m0 + wr * 64 + mi * 16 + (l >> 4) * 4;
      int gc = n0 + wc * 64 + ni * 16 + (l & 15);
#pragma unroll
      for (int j = 0; j < 4; ++j) {
        if (BF16OUT)
          ((unsigned short*)Cv)[(size_t)(gr + j) * N + gc] = f2bf(acc[mi][ni][j]);
        else
          ((float*)Cv + (size_t)blockIdx.z * M * N)[(size_t)(gr + j) * N + gc] = acc[mi][ni][j];
      }
    }
}

// reduce 4 partial C buffers -> dbc (1M floats, float4)
__global__ __launch_bounds__(256) void redux4_k(const float4* __restrict__ part,
                                                float4* __restrict__ out) {
  int i = blockIdx.x * 256 + threadIdx.x;   // 262144 float4
  const int STR = 262144;
  float4 a = part[i], b = part[i + STR], c = part[i + 2 * STR], d = part[i + 3 * STR];
  out[i] = make_float4(a.x + b.x + c.x + d.x, a.y + b.y + c.y + d.y,
                       a.z + b.z + c.z + d.z, a.w + b.w + c.w + d.w);
}

// ---------------- depthwise causal conv(4) + bias + SiLU (bf16 in/out) ----------------
#define CONV_L 16
__global__ __launch_bounds__(256) void conv_silu_k(
    const unsigned short* __restrict__ xzb, const float* __restrict__ cw,
    const float* __restrict__ cb, unsigned short* __restrict__ xsb)
{
  const int b = blockIdx.y;
  const int l0 = blockIdx.x * CONV_L;
  const int d = threadIdx.x * 8;
  float w[4][8], bias[8];
#pragma unroll
  for (int i = 0; i < 8; ++i) {
    bias[i] = cb[d + i];
#pragma unroll
    for (int j = 0; j < 4; ++j) w[j][i] = cw[(d + i) * 4 + j];
  }
  const size_t rb = (size_t)b * 4096;
  float win[3][8];
#pragma unroll
  for (int j = 0; j < 3; ++j) {
    int l = l0 - 3 + j;
    if (l >= 0) {
      u16x8 v = *(const u16x8*)(xzb + (rb + l) * 4096 + d);
#pragma unroll
      for (int i = 0; i < 8; ++i) win[j][i] = bf2f(v[i]);
    } else {
#pragma unroll
      for (int i = 0; i < 8; ++i) win[j][i] = 0.f;
    }
  }
  for (int l = l0; l < l0 + CONV_L; ++l) {
    u16x8 v = *(const u16x8*)(xzb + (rb + l) * 4096 + d);
    float cur[8]; u16x8 ob;
#pragma unroll
    for (int i = 0; i < 8; ++i) {
      cur[i] = bf2f(v[i]);
      float u = bias[i] + w[0][i] * win[0][i] + w[1][i] * win[1][i]
                        + w[2][i] * win[2][i] + w[3][i] * cur[i];
      float s = u / (1.f + __expf(-u));
      ob[i] = f2bf(s);
    }
    *(u16x8*)(xsb + (rb + l) * 2048 + d) = ob;
#pragma unroll
    for (int i = 0; i < 8; ++i) { win[0][i] = win[1][i]; win[1][i] = win[2][i]; win[2][i] = cur[i]; }
  }
}

// ---------------- chunk-parallel selective scan (packed f32x2 math) ----------------
__global__ __launch_bounds__(256) void scan_p1(
    const unsigned short* __restrict__ xsb16, const float* __restrict__ dbc,
    const float* __restrict__ dtw, const float* __restrict__ dtb,
    const float* __restrict__ alog,
    float* __restrict__ Sg, float* __restrict__ cdg)
{
  const int chunk = blockIdx.x;
  const int d0 = blockIdx.y * 256;
  const int b = blockIdx.z;
  const int tid = threadIdx.x;
  const size_t rowbase = (size_t)b * 4096 + chunk * TC;

  __shared__ __align__(16) unsigned short xsS[TH][256];
  __shared__ __align__(16) float bS[TC][16];
  __shared__ float drS[TC];

  if (tid < TC) drS[tid] = dbc[(rowbase + tid) * 128];
  for (int i = tid; i < TC * 16; i += 256) {
    int t = i >> 4, q = i & 15;
    bS[t][q] = dbc[(rowbase + t) * 128 + 1 + q];
  }

  const int d = d0 + tid;
  const float wdt = dtw[d], bdt = dtb[d];
  float adn[16];
  bool ok = true;
#pragma unroll
  for (int k = 0; k < 4; ++k) {
    float4 a4 = *(const float4*)(alog + (size_t)d * 16 + k * 4);
    adn[4 * k + 0] = -__expf(a4.x); adn[4 * k + 1] = -__expf(a4.y);
    adn[4 * k + 2] = -__expf(a4.z); adn[4 * k + 3] = -__expf(a4.w);
  }
#pragma unroll
  for (int n = 0; n < 16; ++n)
    ok = ok && (fabsf(adn[n] + (float)(n + 1)) <= 1e-3f * (float)(n + 1));

  f32x2 h2[8];
#pragma unroll
  for (int k = 0; k < 8; ++k) h2[k] = (f32x2){0.f, 0.f};
  float cd = 0.f;

  for (int half = 0; half < 2; ++half) {
    if (half) __syncthreads();
    for (int i = tid; i < TH * 32; i += 256) {
      int tt = i >> 5, q = i & 31;
      *(u16x8*)&xsS[tt][q * 8] =
          *(const u16x8*)(xsb16 + (rowbase + half * TH + tt) * 2048 + d0 + q * 8);
    }
    __syncthreads();

    if (ok) {
      for (int tt = 0; tt < TH; ++tt) {
        int t = half * TH + tt;
        float pre = fmaf(drS[t], wdt, bdt);
        float e = __expf(pre);
        float dlt = (pre > 20.f) ? pre : __logf(1.f + e);
        float xv = bf2f(xsS[tt][tid]);
        float dx = dlt * xv;
        cd += dlt;
        float r = __expf(-dlt);
        float r2 = r * r;
        f32x2 s2 = (f32x2){r2, r2};
        f32x2 rp2[8];
        rp2[0] = (f32x2){r, r2};
#pragma unroll
        for (int k = 1; k < 8; ++k) rp2[k] = rp2[k - 1] * s2;
        f32x4 Bv[4];
#pragma unroll
        for (int k = 0; k < 4; ++k) Bv[k] = ((const f32x4*)&bS[t][0])[k];
        f32x2 dx2 = (f32x2){dx, dx};
#pragma unroll
        for (int k = 0; k < 4; ++k) {
          f32x2 blo = __builtin_shufflevector(Bv[k], Bv[k], 0, 1);
          f32x2 bhi = __builtin_shufflevector(Bv[k], Bv[k], 2, 3);
          h2[2 * k]     = rp2[2 * k]     * h2[2 * k]     + dx2 * blo;
          h2[2 * k + 1] = rp2[2 * k + 1] * h2[2 * k + 1] + dx2 * bhi;
        }
      }
    } else {
      for (int tt = 0; tt < TH; ++tt) {
        int t = half * TH + tt;
        float pre = fmaf(drS[t], wdt, bdt);
        float e = __expf(pre);
        float dlt = (pre > 20.f) ? pre : __logf(1.f + e);
        float xv = bf2f(xsS[tt][tid]);
        float dx = dlt * xv;
        cd += dlt;
        f32x4 Bv[4];
#pragma unroll
        for (int k = 0; k < 4; ++k) Bv[k] = ((const f32x4*)&bS[t][0])[k];
#pragma unroll
        for (int n = 0; n < 16; ++n) {
          float dA = __expf(adn[n] * dlt);
          h2[n >> 1][n & 1] = fmaf(dA, h2[n >> 1][n & 1], dx * Bv[n >> 2][n & 3]);
        }
      }
    }
  }
  cdg[(size_t)(b * NC + chunk) * 2048 + d] = cd;
  float* Sp = Sg + ((size_t)(b * NC + chunk) * 32768 + (size_t)d * 16);
#pragma unroll
  for (int k = 0; k < 4; ++k)
    ((float4*)Sp)[k] = make_float4(h2[2 * k][0], h2[2 * k][1], h2[2 * k + 1][0], h2[2 * k + 1][1]);
}

// Phase 2: prefix scan across chunks, IN-PLACE: Sg[c] := state entering chunk c.
__global__ __launch_bounds__(256) void scan_p2(
    float* __restrict__ Sg, const float* __restrict__ cdg,
    const float* __restrict__ alog)
{
  int g = blockIdx.x * 256 + threadIdx.x;   // 65536 = B*D*N
  int b = g >> 15, dn = g & 32767;
  int d = dn >> 4;
  float adn = -__expf(alog[dn]);
  float h = 0.f;
  for (int c = 0; c < NC; ++c) {
    size_t o = (size_t)(b * NC + c) * 32768 + dn;
    float S = Sg[o];
    float P = __expf(adn * cdg[(size_t)(b * NC + c) * 2048 + d]);
    Sg[o] = h;
    h = fmaf(P, h, S);
  }
}

__global__ __launch_bounds__(256) void scan_p3(
    const unsigned short* __restrict__ xsb16, const float* __restrict__ dbc,
    const float* __restrict__ dtw, const float* __restrict__ dtb,
    const float* __restrict__ alog, const float* __restrict__ Dp,
    const unsigned short* __restrict__ xzb, const float* __restrict__ Hg,
    unsigned short* __restrict__ gb)
{
  const int chunk = blockIdx.x;
  const int d0 = blockIdx.y * 256;
  const int b = blockIdx.z;
  const int tid = threadIdx.x;
  const size_t rowbase = (size_t)b * 4096 + chunk * TC;

  __shared__ __align__(16) unsigned short xsS[TH][256];
  __shared__ __align__(16) float bcS[TC][32];

  for (int i = tid; i < TC * 32; i += 256) {
    int t = i >> 5, q = i & 31;
    bcS[t][q] = dbc[(rowbase + t) * 128 + 1 + q];
  }

  const int d = d0 + tid;
  const float wdt = dtw[d], bdt = dtb[d], Dd = Dp[d];
  const float* __restrict__ drp = dbc + rowbase * 128;
  float adn[16];
  bool ok = true;
#pragma unroll
  for (int k = 0; k < 4; ++k) {
    float4 a4 = *(const float4*)(alog + (size_t)d * 16 + k * 4);
    adn[4 * k + 0] = -__expf(a4.x); adn[4 * k + 1] = -__expf(a4.y);
    adn[4 * k + 2] = -__expf(a4.z); adn[4 * k + 3] = -__expf(a4.w);
  }
#pragma unroll
  for (int n = 0; n < 16; ++n)
    ok = ok && (fabsf(adn[n] + (float)(n + 1)) <= 1e-3f * (float)(n + 1));

  f32x2 h2[8];
  {
    const float* Hp = Hg + ((size_t)(b * NC + chunk) * 32768 + (size_t)d * 16);
#pragma unroll
    for (int k = 0; k < 4; ++k) {
      float4 h4 = ((const float4*)Hp)[k];
      h2[2 * k]     = (f32x2){h4.x, h4.y};
      h2[2 * k + 1] = (f32x2){h4.z, h4.w};
    }
  }

  for (int half = 0; half < 2; ++half) {
    if (half) __syncthreads();
    for (int i = tid; i < TH * 32; i += 256) {
      int tt = i >> 5, q = i & 31;
      *(u16x8*)&xsS[tt][q * 8] =
          *(const u16x8*)(xsb16 + (rowbase + half * TH + tt) * 2048 + d0 + q * 8);
    }
    __syncthreads();

    if (ok) {
      for (int tt = 0; tt < TH; ++tt) {
        int t = half * TH + tt;
        float pre = fmaf(drp[(size_t)t * 128], wdt, bdt);
        float e = __expf(pre);
        float dlt = (pre > 20.f) ? pre : __logf(1.f + e);
        float xv = bf2f(xsS[tt][tid]);
        float dx = dlt * xv;
        float r = __expf(-dlt);
        float r2 = r * r;
        f32x2 s2 = (f32x2){r2, r2};
        f32x2 rp2[8];
        rp2[0] = (f32x2){r, r2};
#pragma unroll
        for (int k = 1; k < 8; ++k) rp2[k] = rp2[k - 1] * s2;
        f32x4 Bv[4], Cv[4];
#pragma unroll
        for (int k = 0; k < 4; ++k) {
          Bv[k] = ((const f32x4*)&bcS[t][0])[k];
          Cv[k] = ((const f32x4*)&bcS[t][16])[k];
        }
        f32x2 dx2 = (f32x2){dx, dx};
        f32x2 yp2[4];
#pragma unroll
        for (int k = 0; k < 4; ++k) yp2[k] = (f32x2){0.f, 0.f};
#pragma unroll
        for (int k = 0; k < 4; ++k) {
          f32x2 blo = __builtin_shufflevector(Bv[k], Bv[k], 0, 1);
          f32x2 bhi = __builtin_shufflevector(Bv[k], Bv[k], 2, 3);
          f32x2 clo = __builtin_shufflevector(Cv[k], Cv[k], 0, 1);
          f32x2 chi = __builtin_shufflevector(Cv[k], Cv[k], 2, 3);
          h2[2 * k]     = rp2[2 * k]     * h2[2 * k]     + dx2 * blo;
          h2[2 * k + 1] = rp2[2 * k + 1] * h2[2 * k + 1] + dx2 * bhi;
          yp2[k] = h2[2 * k] * clo + yp2[k];
          yp2[k] = h2[2 * k + 1] * chi + yp2[k];
        }
        f32x2 ys = (yp2[0] + yp2[1]) + (yp2[2] + yp2[3]);
        float y = ys[0] + ys[1] + Dd * xv;
        xsS[tt][tid] = f2bf(y);
      }
    } else {
      for (int tt = 0; tt < TH; ++tt) {
        int t = half * TH + tt;
        float pre = fmaf(drp[(size_t)t * 128], wdt, bdt);
        float e = __expf(pre);
        float dlt = (pre > 20.f) ? pre : __logf(1.f + e);
        float xv = bf2f(xsS[tt][tid]);
        float dx = dlt * xv;
        f32x4 Bv[4], Cv[4];
#pragma unroll
        for (int k = 0; k < 4; ++k) {
          Bv[k] = ((const f32x4*)&bcS[t][0])[k];
          Cv[k] = ((const f32x4*)&bcS[t][16])[k];
        }
        float yp[4];
        yp[0] = Dd * xv; yp[1] = 0.f; yp[2] = 0.f; yp[3] = 0.f;
#pragma unroll
        for (int n = 0; n < 16; ++n) {
          float dA = __expf(adn[n] * dlt);
          h2[n >> 1][n & 1] = fmaf(dA, h2[n >> 1][n & 1], dx * Bv[n >> 2][n & 3]);
          yp[n & 3] = fmaf(h2[n >> 1][n & 1], Cv[n >> 2][n & 3], yp[n & 3]);
        }
        float y = (yp[0] + yp[1]) + (yp[2] + yp[3]);
        xsS[tt][tid] = f2bf(y);
      }
    }
    __syncthreads();

    for (int i = tid; i < TH * 32; i += 256) {
      int tt = i >> 5, q = i & 31;
      size_t row = rowbase + half * TH + tt;
      u16x8 yv = *(const u16x8*)&xsS[tt][q * 8];
      u16x8 zv = *(const u16x8*)(xzb + row * 4096 + 2048 + d0 + q * 8);
      u16x8 ov;
#pragma unroll
      for (int j = 0; j < 8; ++j) {
        float z = bf2f(zv[j]);
        float s = z / (1.f + __expf(-z));
        ov[j] = f2bf(bf2f(yv[j]) * s);
      }
      *(u16x8*)(gb + row * 2048 + d0 + q * 8) = ov;
    }
  }
}

extern "C" void kernel_launch(void* const* d_in, const int* in_sizes, int n_in,
                              void* d_out, int out_size, void* d_ws, size_t ws_size,
                              hipStream_t stream) {
  const float* x    = (const float*)d_in[0];
  const float* ipw  = (const float*)d_in[1];
  const float* cw   = (const float*)d_in[2];
  const float* cb   = (const float*)d_in[3];
  const float* xpw  = (const float*)d_in[4];
  const float* dtw  = (const float*)d_in[5];
  const float* dtb  = (const float*)d_in[6];
  const float* alog = (const float*)d_in[7];
  const float* Dp   = (const float*)d_in[8];
  const float* opw  = (const float*)d_in[9];
  float* out = (float*)d_out;

  char* p = (char*)d_ws;
  unsigned short* xb   = (unsigned short*)p; p += (size_t)8388608 * 2;   // x bf16           (16 MiB)
  unsigned short* wb1  = (unsigned short*)p; p += (size_t)4194304 * 2;   // in_proj_w bf16   (8 MiB)
  unsigned short* wb2  = (unsigned short*)p; p += (size_t)2097152 * 2;   // out_proj_w bf16  (4 MiB)
  unsigned short* xwp  = (unsigned short*)p; p += (size_t)262144 * 2;    // padded x_proj_w  (0.5 MiB)
  unsigned short* xzb  = (unsigned short*)p; p += (size_t)33554432 * 2;  // in_proj out bf16 (64 MiB)
  unsigned short* xsb16= (unsigned short*)p; p += (size_t)16777216 * 2;  // conv+silu bf16   (32 MiB)
  float*          dbc  = (float*)p;          p += (size_t)1048576 * 4;   // x_proj out fp32  (4 MiB)
  unsigned short* gb   = (unsigned short*)p; p += (size_t)16777216 * 2;  // y*silu(z) bf16   (32 MiB)
  float*          Sg   = (float*)p;          p += (size_t)8388608 * 4;   // chunk states S->H in-place (32 MiB)
  float*          cdg  = (float*)p;          p += (size_t)524288 * 4;    // chunk decay sums (2 MiB)
  float*          dbcp = Sg;                                             // 4 split-K partials (alias Sg, 16 MiB)

  prep_k<<<dim3(512, 4), 256, 0, stream>>>(
      (const float4*)x, (const float4*)ipw, (const float4*)opw, xpw,
      (ushort4*)xb, (ushort4*)wb1, (ushort4*)wb2, xwp);

  gemm8p<true, true><<<512, 512, 0, stream>>>(xb, wb1, xzb, 8192, 4096, 1024);
  conv_silu_k<<<dim3(4096 / CONV_L, 2), 256, 0, stream>>>(xzb, cw, cb, xsb16);

  gemm2p<false, false><<<dim3(64, 1, 4), 256, 0, stream>>>(xsb16, xwp, dbcp, 8192, 128, 2048);
  redux4_k<<<1024, 256, 0, stream>>>((const float4*)dbcp, (float4*)dbc);

  scan_p1<<<dim3(NC, 8, 2), 256, 0, stream>>>(xsb16, dbc, dtw, dtb, alog, Sg, cdg);
  scan_p2<<<256, 256, 0, stream>>>(Sg, cdg, alog);
  scan_p3<<<dim3(NC, 8, 2), 256, 0, stream>>>(xsb16, dbc, dtw, dtb, alog, Dp, xzb, Sg, gb);

  gemm2p<false, true><<<dim3(512, 1, 1), 256, 0, stream>>>(gb, wb2, out, 8192, 1024, 2048);
}